// Round 8
// baseline (686.900 us; speedup 1.0000x reference)
//
#include <hip/hip_runtime.h>
#include <hip/hip_bf16.h>
#include <math.h>

#define BB 256
#define TT 512
#define DIN 64
#define ZZ 32
#define HH 64

typedef __attribute__((ext_vector_type(4))) float f32x4;
typedef __attribute__((ext_vector_type(8))) __bf16 bf16x8;

__device__ __forceinline__ f32x4 mfma16(bf16x8 a, bf16x8 b, f32x4 c) {
  return __builtin_amdgcn_mfma_f32_16x16x32_bf16(a, b, c, 0, 0, 0);
}

// elu = min(v, e^v - 1): identical for v<=0, exact for v>0, inf-safe.
__device__ __forceinline__ float elu1(float v) {
  return fminf(v, __expf(v) - 1.f);
}
__device__ __forceinline__ f32x4 elu4(f32x4 v) {
  f32x4 r;
  r.x = elu1(v.x); r.y = elu1(v.y); r.z = elu1(v.z); r.w = elu1(v.w);
  return r;
}

// pack two f32x4 (tile0 regs, tile1 regs) into a bf16x8 MFMA operand.
// Slot (q,e) holds k = 16*(e>>2) + 4q + (e&3) == neuron held by D tiles.
__device__ __forceinline__ bf16x8 pack2(f32x4 a, f32x4 b) {
  bf16x8 r;
  r[0] = (__bf16)a.x; r[1] = (__bf16)a.y; r[2] = (__bf16)a.z; r[3] = (__bf16)a.w;
  r[4] = (__bf16)b.x; r[5] = (__bf16)b.y; r[6] = (__bf16)b.z; r[7] = (__bf16)b.w;
  return r;
}

// hi/lo split pack: hi = RNE bf16, lo = bf16(v - float(hi)).
__device__ __forceinline__ void packhl(f32x4 a, f32x4 b, bf16x8& hi, bf16x8& lo) {
  hi = pack2(a, b);
  f32x4 ra, rb;
  ra.x = (float)hi[0]; ra.y = (float)hi[1]; ra.z = (float)hi[2]; ra.w = (float)hi[3];
  rb.x = (float)hi[4]; rb.y = (float)hi[5]; rb.z = (float)hi[6]; rb.w = (float)hi[7];
  lo = pack2(a - ra, b - rb);
}

__device__ __forceinline__ bf16x8 ldw(const float* rowp, int o1, int o2) {
  f32x4 a = *reinterpret_cast<const f32x4*>(rowp + o1);
  f32x4 b = *reinterpret_cast<const f32x4*>(rowp + o2);
  return pack2(a, b);
}
__device__ __forceinline__ void ldw2(const float* rowp, int o1, int o2,
                                     bf16x8& hi, bf16x8& lo) {
  f32x4 a = *reinterpret_cast<const f32x4*>(rowp + o1);
  f32x4 b = *reinterpret_cast<const f32x4*>(rowp + o2);
  packhl(a, b, hi, lo);
}

// tanh via exp + raw v_rcp (rel err ~1ulp fp32 -- far below bf16 noise).
__device__ __forceinline__ float tanh1(float x) {
  float t = __expf(2.f * x);
  return fmaf(-2.f, __builtin_amdgcn_rcpf(t + 1.f), 1.f);
}
__device__ __forceinline__ f32x4 tanh4(f32x4 v) {
  f32x4 r;
  r.x = tanh1(v.x); r.y = tanh1(v.y); r.z = tanh1(v.z); r.w = tanh1(v.w);
  return r;
}

// ---------------------------------------------------------------------------
// prep_kernel: P0[b,t] = (bi0+bh0) + x[b,t] @ Wi0^T for all 131072 rows.
// (unchanged from R6, verified passing)
// ---------------------------------------------------------------------------
__global__ __launch_bounds__(256, 2) void prep_kernel(
    const float* __restrict__ x,
    const float* __restrict__ Wi0,
    const float* __restrict__ bi0, const float* __restrict__ bh0,
    float* __restrict__ p0)
{
  const int lane = threadIdx.x & 63;
  const int wv = threadIdx.x >> 6;
  const int q = lane >> 4, c = lane & 15;

  bf16x8 Wh[2][2], Wl[2][2];   // [kt][mt]
  #pragma unroll
  for (int kt = 0; kt < 2; ++kt)
    #pragma unroll
    for (int mt = 0; mt < 2; ++mt)
      ldw2(Wi0 + (16 * mt + c) * 64, 32 * kt + 4 * q, 32 * kt + 16 + 4 * q,
           Wh[kt][mt], Wl[kt][mt]);
  f32x4 B0[2];
  #pragma unroll
  for (int mt = 0; mt < 2; ++mt)
    B0[mt] = *reinterpret_cast<const f32x4*>(bi0 + 16 * mt + 4 * q) +
             *reinterpret_cast<const f32x4*>(bh0 + 16 * mt + 4 * q);

  const unsigned row = blockIdx.x * 64u + (unsigned)wv * 16u + (unsigned)c;
  const float* xp = x + (size_t)row * DIN;
  f32x4 x0 = *reinterpret_cast<const f32x4*>(xp + 4 * q);
  f32x4 x1 = *reinterpret_cast<const f32x4*>(xp + 16 + 4 * q);
  f32x4 x2 = *reinterpret_cast<const f32x4*>(xp + 32 + 4 * q);
  f32x4 x3 = *reinterpret_cast<const f32x4*>(xp + 48 + 4 * q);
  bf16x8 xf0 = pack2(x0, x1), xf1 = pack2(x2, x3);

  float* pout = p0 + (size_t)row * ZZ;
  #pragma unroll
  for (int mt = 0; mt < 2; ++mt) {
    f32x4 a = mfma16(Wh[0][mt], xf0, B0[mt]);
    a = mfma16(Wl[0][mt], xf0, a);
    a = mfma16(Wh[1][mt], xf1, a);
    a = mfma16(Wl[1][mt], xf1, a);
    *reinterpret_cast<f32x4*>(pout + 16 * mt + 4 * q) = a;
  }
}

// ---------------------------------------------------------------------------
// rnn_kernel: fused 64-wide recurrence (math identical to R6), TWO independent
// 16-batch chains per wave interleaved (8 waves x 32 batches). Chain B's
// instructions fill chain A's dependency-latency stalls (and vice versa) --
// attacking the ~650 cy/step of exposed latency R6/R7 measured.
// ---------------------------------------------------------------------------
__global__ __launch_bounds__(64, 1) void rnn_kernel(
    const float* __restrict__ p0buf,
    const float* __restrict__ Wh0,
    const float* __restrict__ Wi1, const float* __restrict__ Wh1,
    const float* __restrict__ bi1, const float* __restrict__ bh1,
    const float* __restrict__ h0g,
    float* __restrict__ rnn, float* __restrict__ out)
{
  const int lane = threadIdx.x & 63;
  const int q = lane >> 4, c = lane & 15;
  const int b0 = blockIdx.x * 32;
  const f32x4 Z4 = {0.f, 0.f, 0.f, 0.f};

  // ---- weight A-fragments (hi/lo), shared by both chains ----
  bf16x8 W0h[2], W0l[2];            // Wh0, K=32
  #pragma unroll
  for (int mt = 0; mt < 2; ++mt)
    ldw2(Wh0 + (16 * mt + c) * 32, 4 * q, 16 + 4 * q, W0h[mt], W0l[mt]);
  bf16x8 W1h[2][2], W1l[2][2];      // [kt][mt]; kt0 = Wi1, kt1 = Wh1
  #pragma unroll
  for (int mt = 0; mt < 2; ++mt) {
    ldw2(Wi1 + (16 * mt + c) * 32, 4 * q, 16 + 4 * q, W1h[0][mt], W1l[0][mt]);
    ldw2(Wh1 + (16 * mt + c) * 32, 4 * q, 16 + 4 * q, W1h[1][mt], W1l[1][mt]);
  }
  f32x4 B1[2];
  #pragma unroll
  for (int mt = 0; mt < 2; ++mt)
    B1[mt] = *reinterpret_cast<const f32x4*>(bi1 + 16 * mt + 4 * q) +
             *reinterpret_cast<const f32x4*>(bh1 + 16 * mt + 4 * q);

  // ---- initial states (h0 is batch-broadcast: same for both chains) ----
  bf16x8 Azh0, Azl0, Azh1, Azl1, Bzh0, Bzl0, Bzh1, Bzl1;
  {
    f32x4 u0 = *reinterpret_cast<const f32x4*>(h0g + 4 * q);
    f32x4 u1 = *reinterpret_cast<const f32x4*>(h0g + 16 + 4 * q);
    packhl(u0, u1, Azh0, Azl0);
    Bzh0 = Azh0; Bzl0 = Azl0;
    u0 = *reinterpret_cast<const f32x4*>(h0g + 32 + 4 * q);
    u1 = *reinterpret_cast<const f32x4*>(h0g + 48 + 4 * q);
    packhl(u0, u1, Azh1, Azl1);
    Bzh1 = Azh1; Bzl1 = Azl1;
  }

  const float* ppA = p0buf + (size_t)(b0 + c) * TT * ZZ;
  const float* ppB = ppA + (size_t)16 * TT * ZZ;
  float* prA = rnn + (size_t)(b0 + c) * TT * ZZ;
  float* prB = prA + (size_t)16 * TT * ZZ;
  float* poA = out + (size_t)(b0 + c) * TT * ZZ;
  float* poB = poA + (size_t)16 * TT * ZZ;

  auto ldp = [&](const float* pp, int t, f32x4& m0, f32x4& m1) {
    const float* pt = pp + (size_t)t * ZZ;
    m0 = *reinterpret_cast<const f32x4*>(pt + 4 * q);
    m1 = *reinterpret_cast<const f32x4*>(pt + 16 + 4 * q);
  };

  // ---- peel t=511: compute h0(511) only, per chain ----
  auto PEEL = [&](const float* pp, bf16x8& zh0, bf16x8& zl0) {
    f32x4 Pm0, Pm1;
    ldp(pp, 511, Pm0, Pm1);
    f32x4 dm0 = mfma16(W0h[0], zh0, Pm0);
    f32x4 dm1 = mfma16(W0h[1], zh0, Pm1);
    f32x4 dl0 = mfma16(W0l[0], zh0, mfma16(W0h[0], zl0, Z4));
    f32x4 dl1 = mfma16(W0l[1], zh0, mfma16(W0h[1], zl0, Z4));
    f32x4 d0 = tanh4(dm0 + dl0), d1 = tanh4(dm1 + dl1);
    packhl(d0, d1, zh0, zl0);
  };
  PEEL(ppA, Azh0, Azl0);
  PEEL(ppB, Bzh0, Bzl0);

  // ---- P0 prefetch: 3 rotating register pairs per chain, distance 3 ----
  f32x4 PaA0, PaA1, PbA0, PbA1, PcA0, PcA1;
  f32x4 PaB0, PaB1, PbB0, PbB1, PcB0, PcB1;
  ldp(ppA, 510, PaA0, PaA1);  ldp(ppB, 510, PaB0, PaB1);
  ldp(ppA, 509, PbA0, PbA1);  ldp(ppB, 509, PbB0, PbB1);
  ldp(ppA, 508, PcA0, PcA1);  ldp(ppB, 508, PcB0, PcB1);

  // STEP: one chain, one timestep (identical math to R6's SLOT).
  auto STEP = [&](int t, f32x4& Pm0, f32x4& Pm1,
                  bf16x8& zh0, bf16x8& zl0, bf16x8& zh1, bf16x8& zl1,
                  const float* pp, float* pr, float* po, bool reload) {
    // h0-outputs (K=32): 3 MFMA x 2 tiles
    f32x4 dm0 = mfma16(W0h[0], zh0, Pm0);
    f32x4 dm1 = mfma16(W0h[1], zh0, Pm1);
    f32x4 dl0 = mfma16(W0l[0], zh0, mfma16(W0h[0], zl0, Z4));
    f32x4 dl1 = mfma16(W0l[1], zh0, mfma16(W0h[1], zl0, Z4));
    // h1-outputs (K=64): 6 MFMA x 2 tiles
    f32x4 ea0 = mfma16(W1h[1][0], zh1, mfma16(W1h[0][0], zh0, B1[0]));
    f32x4 ea1 = mfma16(W1h[1][1], zh1, mfma16(W1h[0][1], zh0, B1[1]));
    f32x4 eb0 = mfma16(W1h[1][0], zl1, mfma16(W1h[0][0], zl0, Z4));
    f32x4 eb1 = mfma16(W1h[1][1], zl1, mfma16(W1h[0][1], zl0, Z4));
    f32x4 ec0 = mfma16(W1l[1][0], zh1, mfma16(W1l[0][0], zh0, Z4));
    f32x4 ec1 = mfma16(W1l[1][1], zh1, mfma16(W1l[0][1], zh0, Z4));
    if (reload) {
      const int tl = t >= 3 ? t - 3 : 0;
      ldp(pp, tl, Pm0, Pm1);
    }
    f32x4 d0 = tanh4(dm0 + dl0), d1 = tanh4(dm1 + dl1);
    f32x4 e0 = tanh4(ea0 + (eb0 + ec0)), e1 = tanh4(ea1 + (eb1 + ec1));
    // store h1(t+1)
    float* prt = pr + (size_t)(t + 1) * ZZ;
    *reinterpret_cast<f32x4*>(prt + 4 * q) = e0;
    *reinterpret_cast<f32x4*>(prt + 16 + 4 * q) = e1;
    if (t == 510) {   // h1(511) also goes to out row 511
      float* pot = po + (size_t)511 * ZZ;
      *reinterpret_cast<f32x4*>(pot + 4 * q) = e0;
      *reinterpret_cast<f32x4*>(pot + 16 + 4 * q) = e1;
    }
    packhl(d0, d1, zh0, zl0);
    packhl(e0, e1, zh1, zl1);
  };

  #pragma unroll 1
  for (int g = 0; g < 170; ++g) {
    const int tb = 510 - 3 * g;
    STEP(tb,     PaA0, PaA1, Azh0, Azl0, Azh1, Azl1, ppA, prA, poA, true);
    STEP(tb,     PaB0, PaB1, Bzh0, Bzl0, Bzh1, Bzl1, ppB, prB, poB, true);
    STEP(tb - 1, PbA0, PbA1, Azh0, Azl0, Azh1, Azl1, ppA, prA, poA, true);
    STEP(tb - 1, PbB0, PbB1, Bzh0, Bzl0, Bzh1, Bzl1, ppB, prB, poB, true);
    STEP(tb - 2, PcA0, PcA1, Azh0, Azl0, Azh1, Azl1, ppA, prA, poA, true);
    STEP(tb - 2, PcB0, PcB1, Bzh0, Bzl0, Bzh1, Bzl1, ppB, prB, poB, true);
  }
  STEP(0, PaA0, PaA1, Azh0, Azl0, Azh1, Azl1, ppA, prA, poA, false);
  STEP(0, PaB0, PaB1, Bzh0, Bzl0, Bzh1, Bzl1, ppB, prB, poB, false);
}

// ---------------------------------------------------------------------------
// ODE kernel: unchanged from R6 (verified passing).
// ---------------------------------------------------------------------------
__global__ __launch_bounds__(256, 2) void ode_kernel(
    const float* __restrict__ rnn,
    const float* __restrict__ w1, const float* __restrict__ b1,
    const float* __restrict__ w2, const float* __restrict__ b2,
    const float* __restrict__ w3, const float* __restrict__ b3,
    float* __restrict__ out)
{
  const int lane = threadIdx.x & 63;
  const int wv = threadIdx.x >> 6;
  const int q = lane >> 4, c = lane & 15;

  bf16x8 W1[4], W2[2][4], W3[2][2];
  f32x4 BZ1[4], BZ2[4], BZ3[2];
  #pragma unroll
  for (int mt = 0; mt < 4; ++mt) {
    W1[mt] = ldw(w1 + (16 * mt + c) * 32, 4 * q, 16 + 4 * q);
    BZ1[mt] = *reinterpret_cast<const f32x4*>(b1 + 16 * mt + 4 * q);
    BZ2[mt] = *reinterpret_cast<const f32x4*>(b2 + 16 * mt + 4 * q);
  }
  #pragma unroll
  for (int kt = 0; kt < 2; ++kt)
    #pragma unroll
    for (int mt = 0; mt < 4; ++mt)
      W2[kt][mt] = ldw(w2 + (16 * mt + c) * 64, 32 * kt + 4 * q, 32 * kt + 16 + 4 * q);
  #pragma unroll
  for (int kt = 0; kt < 2; ++kt)
    #pragma unroll
    for (int mt = 0; mt < 2; ++mt)
      W3[kt][mt] = ldw(w3 + (16 * mt + c) * 64, 32 * kt + 4 * q, 32 * kt + 16 + 4 * q);
  #pragma unroll
  for (int mt = 0; mt < 2; ++mt)
    BZ3[mt] = *reinterpret_cast<const f32x4*>(b3 + 16 * mt + 4 * q);

  const unsigned row = 16u * (blockIdx.x * 4u + (unsigned)wv) + (unsigned)c;
  const unsigned bb = row / 511u, tp = row - bb * 511u;
  const float* srcp = rnn + ((size_t)bb * TT + tp + 1) * ZZ;
  f32x4 y0 = *reinterpret_cast<const f32x4*>(srcp + 4 * q);
  f32x4 y1 = *reinterpret_cast<const f32x4*>(srcp + 16 + 4 * q);

  f32x4 k0, k1, ks0, ks1;

  auto feval = [&](bf16x8 xf, f32x4& o0, f32x4& o1) {
    f32x4 a[4];
    #pragma unroll
    for (int mt = 0; mt < 4; ++mt) a[mt] = mfma16(W1[mt], xf, BZ1[mt]);
    #pragma unroll
    for (int mt = 0; mt < 4; ++mt) a[mt] = elu4(a[mt]);
    bf16x8 h10 = pack2(a[0], a[1]), h11 = pack2(a[2], a[3]);
    f32x4 g[4];
    #pragma unroll
    for (int mt = 0; mt < 4; ++mt)
      g[mt] = mfma16(W2[1][mt], h11, mfma16(W2[0][mt], h10, BZ2[mt]));
    #pragma unroll
    for (int mt = 0; mt < 4; ++mt) g[mt] = elu4(g[mt]);
    bf16x8 h20 = pack2(g[0], g[1]), h21 = pack2(g[2], g[3]);
    o0 = mfma16(W3[1][0], h21, mfma16(W3[0][0], h20, BZ3[0]));
    o1 = mfma16(W3[1][1], h21, mfma16(W3[0][1], h20, BZ3[1]));
  };

  const float hs = 0.01f;
  #pragma unroll 1
  for (int it = 0; it < 9; ++it) {
    feval(pack2(y0, y1), k0, k1);
    ks0 = k0; ks1 = k1;
    feval(pack2(y0 + (0.5f * hs) * k0, y1 + (0.5f * hs) * k1), k0, k1);
    ks0 += 2.f * k0; ks1 += 2.f * k1;
    feval(pack2(y0 + (0.5f * hs) * k0, y1 + (0.5f * hs) * k1), k0, k1);
    ks0 += 2.f * k0; ks1 += 2.f * k1;
    feval(pack2(y0 + hs * k0, y1 + hs * k1), k0, k1);
    y0 += (hs / 6.f) * (ks0 + k0);
    y1 += (hs / 6.f) * (ks1 + k1);
  }

  float* dstp = out + ((size_t)bb * TT + tp) * ZZ;
  *reinterpret_cast<f32x4*>(dstp + 4 * q) = y0;
  *reinterpret_cast<f32x4*>(dstp + 16 + 4 * q) = y1;
}

// ---------------------------------------------------------------------------
extern "C" void kernel_launch(void* const* d_in, const int* in_sizes, int n_in,
                              void* d_out, int out_size, void* d_ws, size_t ws_size,
                              hipStream_t stream) {
  const float* x   = (const float*)d_in[0];
  const float* Wi0 = (const float*)d_in[1];
  const float* Wh0 = (const float*)d_in[2];
  const float* bi0 = (const float*)d_in[3];
  const float* bh0 = (const float*)d_in[4];
  const float* Wi1 = (const float*)d_in[5];
  const float* Wh1 = (const float*)d_in[6];
  const float* bi1 = (const float*)d_in[7];
  const float* bh1 = (const float*)d_in[8];
  const float* h0  = (const float*)d_in[9];
  const float* w1  = (const float*)d_in[10];
  const float* b1  = (const float*)d_in[11];
  const float* w2  = (const float*)d_in[12];
  const float* b2  = (const float*)d_in[13];
  const float* w3  = (const float*)d_in[14];
  const float* b3  = (const float*)d_in[15];
  float* out = (float*)d_out;
  float* rnn = (float*)d_ws;      // B*T*Z fp32 = 16.7 MB scratch
  float* p0  = (float*)d_out;     // d_out doubles as P0 scratch; every byte
                                  // is overwritten later (ode rows 0..510,
                                  // rnn row 511) before validation.

  prep_kernel<<<2048, 256, 0, stream>>>(x, Wi0, bi0, bh0, p0);
  // 256 batches = 32 batches/wave (2 chains of 16) * 8 blocks
  rnn_kernel<<<8, 64, 0, stream>>>(p0, Wh0, Wi1, Wh1, bi1, bh1, h0, rnn, out);
  ode_kernel<<<2044, 256, 0, stream>>>(rnn, w1, b1, w2, b2, w3, b3, out);
}

// Round 9
// 606.299 us; speedup vs baseline: 1.1329x; 1.1329x over previous
//
#include <hip/hip_runtime.h>
#include <hip/hip_bf16.h>
#include <math.h>

#define BB 256
#define TT 512
#define DIN 64
#define ZZ 32
#define HH 64

typedef __attribute__((ext_vector_type(4))) float f32x4;
typedef __attribute__((ext_vector_type(8))) __bf16 bf16x8;

__device__ __forceinline__ f32x4 mfma16(bf16x8 a, bf16x8 b, f32x4 c) {
  return __builtin_amdgcn_mfma_f32_16x16x32_bf16(a, b, c, 0, 0, 0);
}

// elu = min(v, e^v - 1): identical for v<=0, exact for v>0, inf-safe.
__device__ __forceinline__ float elu1(float v) {
  return fminf(v, __expf(v) - 1.f);
}
__device__ __forceinline__ f32x4 elu4(f32x4 v) {
  f32x4 r;
  r.x = elu1(v.x); r.y = elu1(v.y); r.z = elu1(v.z); r.w = elu1(v.w);
  return r;
}

// pack two f32x4 (tile0 regs, tile1 regs) into a bf16x8 MFMA operand.
// Slot (q,e) holds k = 16*(e>>2) + 4q + (e&3) == neuron held by D tiles.
__device__ __forceinline__ bf16x8 pack2(f32x4 a, f32x4 b) {
  bf16x8 r;
  r[0] = (__bf16)a.x; r[1] = (__bf16)a.y; r[2] = (__bf16)a.z; r[3] = (__bf16)a.w;
  r[4] = (__bf16)b.x; r[5] = (__bf16)b.y; r[6] = (__bf16)b.z; r[7] = (__bf16)b.w;
  return r;
}

// hi/lo split pack: hi = RNE bf16, lo = bf16(v - float(hi)).
__device__ __forceinline__ void packhl(f32x4 a, f32x4 b, bf16x8& hi, bf16x8& lo) {
  hi = pack2(a, b);
  f32x4 ra, rb;
  ra.x = (float)hi[0]; ra.y = (float)hi[1]; ra.z = (float)hi[2]; ra.w = (float)hi[3];
  rb.x = (float)hi[4]; rb.y = (float)hi[5]; rb.z = (float)hi[6]; rb.w = (float)hi[7];
  lo = pack2(a - ra, b - rb);
}

__device__ __forceinline__ bf16x8 ldw(const float* rowp, int o1, int o2) {
  f32x4 a = *reinterpret_cast<const f32x4*>(rowp + o1);
  f32x4 b = *reinterpret_cast<const f32x4*>(rowp + o2);
  return pack2(a, b);
}
__device__ __forceinline__ void ldw2(const float* rowp, int o1, int o2,
                                     bf16x8& hi, bf16x8& lo) {
  f32x4 a = *reinterpret_cast<const f32x4*>(rowp + o1);
  f32x4 b = *reinterpret_cast<const f32x4*>(rowp + o2);
  packhl(a, b, hi, lo);
}

// tanh via exp + raw v_rcp (rel err ~1ulp fp32 -- far below bf16 noise).
__device__ __forceinline__ float tanh1(float x) {
  float t = __expf(2.f * x);
  return fmaf(-2.f, __builtin_amdgcn_rcpf(t + 1.f), 1.f);
}
__device__ __forceinline__ f32x4 tanh4(f32x4 v) {
  f32x4 r;
  r.x = tanh1(v.x); r.y = tanh1(v.y); r.z = tanh1(v.z); r.w = tanh1(v.w);
  return r;
}

// ---------------------------------------------------------------------------
// prep_kernel: P0[b,t] = (bi0+bh0) + x[b,t] @ Wi0^T for all 131072 rows.
// (unchanged from R6, verified passing)
// ---------------------------------------------------------------------------
__global__ __launch_bounds__(256, 2) void prep_kernel(
    const float* __restrict__ x,
    const float* __restrict__ Wi0,
    const float* __restrict__ bi0, const float* __restrict__ bh0,
    float* __restrict__ p0)
{
  const int lane = threadIdx.x & 63;
  const int wv = threadIdx.x >> 6;
  const int q = lane >> 4, c = lane & 15;

  bf16x8 Wh[2][2], Wl[2][2];   // [kt][mt]
  #pragma unroll
  for (int kt = 0; kt < 2; ++kt)
    #pragma unroll
    for (int mt = 0; mt < 2; ++mt)
      ldw2(Wi0 + (16 * mt + c) * 64, 32 * kt + 4 * q, 32 * kt + 16 + 4 * q,
           Wh[kt][mt], Wl[kt][mt]);
  f32x4 B0[2];
  #pragma unroll
  for (int mt = 0; mt < 2; ++mt)
    B0[mt] = *reinterpret_cast<const f32x4*>(bi0 + 16 * mt + 4 * q) +
             *reinterpret_cast<const f32x4*>(bh0 + 16 * mt + 4 * q);

  const unsigned row = blockIdx.x * 64u + (unsigned)wv * 16u + (unsigned)c;
  const float* xp = x + (size_t)row * DIN;
  f32x4 x0 = *reinterpret_cast<const f32x4*>(xp + 4 * q);
  f32x4 x1 = *reinterpret_cast<const f32x4*>(xp + 16 + 4 * q);
  f32x4 x2 = *reinterpret_cast<const f32x4*>(xp + 32 + 4 * q);
  f32x4 x3 = *reinterpret_cast<const f32x4*>(xp + 48 + 4 * q);
  bf16x8 xf0 = pack2(x0, x1), xf1 = pack2(x2, x3);

  float* pout = p0 + (size_t)row * ZZ;
  #pragma unroll
  for (int mt = 0; mt < 2; ++mt) {
    f32x4 a = mfma16(Wh[0][mt], xf0, B0[mt]);
    a = mfma16(Wl[0][mt], xf0, a);
    a = mfma16(Wh[1][mt], xf1, a);
    a = mfma16(Wl[1][mt], xf1, a);
    *reinterpret_cast<f32x4*>(pout + 16 * mt + 4 * q) = a;
  }
}

// ---------------------------------------------------------------------------
// rnn_kernel: R6's fused 64-wide recurrence, ONE chain per wave, but packed
// 8 waves/block (2 blocks) => 2 independent chain-waves per SIMD. The CU
// scheduler interleaves the two waves' issue streams in hardware, filling
// each wave's ~55% dependency-stall cycles -- no compiler cooperation needed
// (R8 showed the compiler won't interleave within one wave).
// ---------------------------------------------------------------------------
__global__ __launch_bounds__(512, 1) void rnn_kernel(
    const float* __restrict__ p0buf,
    const float* __restrict__ Wh0,
    const float* __restrict__ Wi1, const float* __restrict__ Wh1,
    const float* __restrict__ bi1, const float* __restrict__ bh1,
    const float* __restrict__ h0g,
    float* __restrict__ rnn, float* __restrict__ out)
{
  const int lane = threadIdx.x & 63;
  const int wv = threadIdx.x >> 6;           // 0..7; wave w -> SIMD w%4
  const int q = lane >> 4, c = lane & 15;
  const int b0 = (blockIdx.x * 8 + wv) * 16; // 16 chains total
  const f32x4 Z4 = {0.f, 0.f, 0.f, 0.f};

  // ---- weight A-fragments (hi/lo) ----
  bf16x8 W0h[2], W0l[2];            // Wh0, K=32
  #pragma unroll
  for (int mt = 0; mt < 2; ++mt)
    ldw2(Wh0 + (16 * mt + c) * 32, 4 * q, 16 + 4 * q, W0h[mt], W0l[mt]);
  bf16x8 W1h[2][2], W1l[2][2];      // [kt][mt]; kt0 = Wi1, kt1 = Wh1
  #pragma unroll
  for (int mt = 0; mt < 2; ++mt) {
    ldw2(Wi1 + (16 * mt + c) * 32, 4 * q, 16 + 4 * q, W1h[0][mt], W1l[0][mt]);
    ldw2(Wh1 + (16 * mt + c) * 32, 4 * q, 16 + 4 * q, W1h[1][mt], W1l[1][mt]);
  }
  f32x4 B1[2];
  #pragma unroll
  for (int mt = 0; mt < 2; ++mt)
    B1[mt] = *reinterpret_cast<const f32x4*>(bi1 + 16 * mt + 4 * q) +
             *reinterpret_cast<const f32x4*>(bh1 + 16 * mt + 4 * q);

  // ---- initial state z = [h0_init; h1_init] ----
  bf16x8 zh0, zl0, zh1, zl1;
  {
    f32x4 u0 = *reinterpret_cast<const f32x4*>(h0g + 4 * q);
    f32x4 u1 = *reinterpret_cast<const f32x4*>(h0g + 16 + 4 * q);
    packhl(u0, u1, zh0, zl0);
    u0 = *reinterpret_cast<const f32x4*>(h0g + 32 + 4 * q);
    u1 = *reinterpret_cast<const f32x4*>(h0g + 48 + 4 * q);
    packhl(u0, u1, zh1, zl1);
  }

  const float* pp = p0buf + (size_t)(b0 + c) * TT * ZZ;
  float* pr = rnn + (size_t)(b0 + c) * TT * ZZ;
  float* po = out + (size_t)(b0 + c) * TT * ZZ;

  auto ldp = [&](int t, f32x4& m0, f32x4& m1) {
    const float* pt = pp + (size_t)t * ZZ;
    m0 = *reinterpret_cast<const f32x4*>(pt + 4 * q);
    m1 = *reinterpret_cast<const f32x4*>(pt + 16 + 4 * q);
  };

  // ---- peel t=511: compute h0(511) only ----
  {
    f32x4 Pm0, Pm1;
    ldp(511, Pm0, Pm1);
    f32x4 dm0 = mfma16(W0h[0], zh0, Pm0);
    f32x4 dm1 = mfma16(W0h[1], zh0, Pm1);
    f32x4 dl0 = mfma16(W0l[0], zh0, mfma16(W0h[0], zl0, Z4));
    f32x4 dl1 = mfma16(W0l[1], zh0, mfma16(W0h[1], zl0, Z4));
    f32x4 d0 = tanh4(dm0 + dl0), d1 = tanh4(dm1 + dl1);
    packhl(d0, d1, zh0, zl0);
  }

  // ---- P0 prefetch: 3 rotating register pairs, distance 3 ----
  f32x4 Pa0, Pa1, Pb0, Pb1, Pc0, Pc1;
  ldp(510, Pa0, Pa1);
  ldp(509, Pb0, Pb1);
  ldp(508, Pc0, Pc1);

  auto SLOT = [&](int t, f32x4& Pm0, f32x4& Pm1, bool reload) {
    // h0-outputs (K=32): 3 MFMA x 2 tiles
    f32x4 dm0 = mfma16(W0h[0], zh0, Pm0);
    f32x4 dm1 = mfma16(W0h[1], zh0, Pm1);
    f32x4 dl0 = mfma16(W0l[0], zh0, mfma16(W0h[0], zl0, Z4));
    f32x4 dl1 = mfma16(W0l[1], zh0, mfma16(W0h[1], zl0, Z4));
    // h1-outputs (K=64): 6 MFMA x 2 tiles
    f32x4 ea0 = mfma16(W1h[1][0], zh1, mfma16(W1h[0][0], zh0, B1[0]));
    f32x4 ea1 = mfma16(W1h[1][1], zh1, mfma16(W1h[0][1], zh0, B1[1]));
    f32x4 eb0 = mfma16(W1h[1][0], zl1, mfma16(W1h[0][0], zl0, Z4));
    f32x4 eb1 = mfma16(W1h[1][1], zl1, mfma16(W1h[0][1], zl0, Z4));
    f32x4 ec0 = mfma16(W1l[1][0], zh1, mfma16(W1l[0][0], zh0, Z4));
    f32x4 ec1 = mfma16(W1l[1][1], zh1, mfma16(W1l[0][1], zh0, Z4));
    if (reload) {
      const int tl = t >= 3 ? t - 3 : 0;
      ldp(tl, Pm0, Pm1);
    }
    f32x4 d0 = tanh4(dm0 + dl0), d1 = tanh4(dm1 + dl1);
    f32x4 e0 = tanh4(ea0 + (eb0 + ec0)), e1 = tanh4(ea1 + (eb1 + ec1));
    // store h1(t+1)
    float* prt = pr + (size_t)(t + 1) * ZZ;
    *reinterpret_cast<f32x4*>(prt + 4 * q) = e0;
    *reinterpret_cast<f32x4*>(prt + 16 + 4 * q) = e1;
    if (t == 510) {   // h1(511) also goes to out row 511
      float* pot = po + (size_t)511 * ZZ;
      *reinterpret_cast<f32x4*>(pot + 4 * q) = e0;
      *reinterpret_cast<f32x4*>(pot + 16 + 4 * q) = e1;
    }
    packhl(d0, d1, zh0, zl0);
    packhl(e0, e1, zh1, zl1);
  };

  #pragma unroll 1
  for (int g = 0; g < 170; ++g) {
    const int tb = 510 - 3 * g;
    SLOT(tb,     Pa0, Pa1, true);
    SLOT(tb - 1, Pb0, Pb1, true);
    SLOT(tb - 2, Pc0, Pc1, true);
  }
  SLOT(0, Pa0, Pa1, false);   // produces h1(1); h0(0) discarded
}

// ---------------------------------------------------------------------------
// ODE kernel: unchanged from R6 (verified passing).
// ---------------------------------------------------------------------------
__global__ __launch_bounds__(256, 2) void ode_kernel(
    const float* __restrict__ rnn,
    const float* __restrict__ w1, const float* __restrict__ b1,
    const float* __restrict__ w2, const float* __restrict__ b2,
    const float* __restrict__ w3, const float* __restrict__ b3,
    float* __restrict__ out)
{
  const int lane = threadIdx.x & 63;
  const int wv = threadIdx.x >> 6;
  const int q = lane >> 4, c = lane & 15;

  bf16x8 W1[4], W2[2][4], W3[2][2];
  f32x4 BZ1[4], BZ2[4], BZ3[2];
  #pragma unroll
  for (int mt = 0; mt < 4; ++mt) {
    W1[mt] = ldw(w1 + (16 * mt + c) * 32, 4 * q, 16 + 4 * q);
    BZ1[mt] = *reinterpret_cast<const f32x4*>(b1 + 16 * mt + 4 * q);
    BZ2[mt] = *reinterpret_cast<const f32x4*>(b2 + 16 * mt + 4 * q);
  }
  #pragma unroll
  for (int kt = 0; kt < 2; ++kt)
    #pragma unroll
    for (int mt = 0; mt < 4; ++mt)
      W2[kt][mt] = ldw(w2 + (16 * mt + c) * 64, 32 * kt + 4 * q, 32 * kt + 16 + 4 * q);
  #pragma unroll
  for (int kt = 0; kt < 2; ++kt)
    #pragma unroll
    for (int mt = 0; mt < 2; ++mt)
      W3[kt][mt] = ldw(w3 + (16 * mt + c) * 64, 32 * kt + 4 * q, 32 * kt + 16 + 4 * q);
  #pragma unroll
  for (int mt = 0; mt < 2; ++mt)
    BZ3[mt] = *reinterpret_cast<const f32x4*>(b3 + 16 * mt + 4 * q);

  const unsigned row = 16u * (blockIdx.x * 4u + (unsigned)wv) + (unsigned)c;
  const unsigned bb = row / 511u, tp = row - bb * 511u;
  const float* srcp = rnn + ((size_t)bb * TT + tp + 1) * ZZ;
  f32x4 y0 = *reinterpret_cast<const f32x4*>(srcp + 4 * q);
  f32x4 y1 = *reinterpret_cast<const f32x4*>(srcp + 16 + 4 * q);

  f32x4 k0, k1, ks0, ks1;

  auto feval = [&](bf16x8 xf, f32x4& o0, f32x4& o1) {
    f32x4 a[4];
    #pragma unroll
    for (int mt = 0; mt < 4; ++mt) a[mt] = mfma16(W1[mt], xf, BZ1[mt]);
    #pragma unroll
    for (int mt = 0; mt < 4; ++mt) a[mt] = elu4(a[mt]);
    bf16x8 h10 = pack2(a[0], a[1]), h11 = pack2(a[2], a[3]);
    f32x4 g[4];
    #pragma unroll
    for (int mt = 0; mt < 4; ++mt)
      g[mt] = mfma16(W2[1][mt], h11, mfma16(W2[0][mt], h10, BZ2[mt]));
    #pragma unroll
    for (int mt = 0; mt < 4; ++mt) g[mt] = elu4(g[mt]);
    bf16x8 h20 = pack2(g[0], g[1]), h21 = pack2(g[2], g[3]);
    o0 = mfma16(W3[1][0], h21, mfma16(W3[0][0], h20, BZ3[0]));
    o1 = mfma16(W3[1][1], h21, mfma16(W3[0][1], h20, BZ3[1]));
  };

  const float hs = 0.01f;
  #pragma unroll 1
  for (int it = 0; it < 9; ++it) {
    feval(pack2(y0, y1), k0, k1);
    ks0 = k0; ks1 = k1;
    feval(pack2(y0 + (0.5f * hs) * k0, y1 + (0.5f * hs) * k1), k0, k1);
    ks0 += 2.f * k0; ks1 += 2.f * k1;
    feval(pack2(y0 + (0.5f * hs) * k0, y1 + (0.5f * hs) * k1), k0, k1);
    ks0 += 2.f * k0; ks1 += 2.f * k1;
    feval(pack2(y0 + hs * k0, y1 + hs * k1), k0, k1);
    y0 += (hs / 6.f) * (ks0 + k0);
    y1 += (hs / 6.f) * (ks1 + k1);
  }

  float* dstp = out + ((size_t)bb * TT + tp) * ZZ;
  *reinterpret_cast<f32x4*>(dstp + 4 * q) = y0;
  *reinterpret_cast<f32x4*>(dstp + 16 + 4 * q) = y1;
}

// ---------------------------------------------------------------------------
extern "C" void kernel_launch(void* const* d_in, const int* in_sizes, int n_in,
                              void* d_out, int out_size, void* d_ws, size_t ws_size,
                              hipStream_t stream) {
  const float* x   = (const float*)d_in[0];
  const float* Wi0 = (const float*)d_in[1];
  const float* Wh0 = (const float*)d_in[2];
  const float* bi0 = (const float*)d_in[3];
  const float* bh0 = (const float*)d_in[4];
  const float* Wi1 = (const float*)d_in[5];
  const float* Wh1 = (const float*)d_in[6];
  const float* bi1 = (const float*)d_in[7];
  const float* bh1 = (const float*)d_in[8];
  const float* h0  = (const float*)d_in[9];
  const float* w1  = (const float*)d_in[10];
  const float* b1  = (const float*)d_in[11];
  const float* w2  = (const float*)d_in[12];
  const float* b2  = (const float*)d_in[13];
  const float* w3  = (const float*)d_in[14];
  const float* b3  = (const float*)d_in[15];
  float* out = (float*)d_out;
  float* rnn = (float*)d_ws;      // B*T*Z fp32 = 16.7 MB scratch
  float* p0  = (float*)d_out;     // d_out doubles as P0 scratch; every byte
                                  // is overwritten later (ode rows 0..510,
                                  // rnn row 511) before validation.

  prep_kernel<<<2048, 256, 0, stream>>>(x, Wi0, bi0, bh0, p0);
  // 16 chains of 16 batches = 2 blocks x 8 waves  => 2 chain-waves per SIMD
  rnn_kernel<<<2, 512, 0, stream>>>(p0, Wh0, Wi1, Wh1, bi1, bh1, h0, rnn, out);
  ode_kernel<<<2044, 256, 0, stream>>>(rnn, w1, b1, w2, b2, w3, b3, out);
}

// Round 10
// 293.494 us; speedup vs baseline: 2.3404x; 2.0658x over previous
//
#include <hip/hip_runtime.h>
#include <hip/hip_bf16.h>
#include <math.h>

#define BB 256
#define TT 512
#define DIN 64
#define ZZ 32
#define HH 64

typedef __attribute__((ext_vector_type(4))) float f32x4;
typedef __attribute__((ext_vector_type(8))) __bf16 bf16x8;
typedef __attribute__((ext_vector_type(4))) __bf16 bf16x4;
typedef __attribute__((ext_vector_type(2))) unsigned int u32x2;
typedef __attribute__((ext_vector_type(4))) unsigned int u32x4;

union FragU { u32x4 u; bf16x8 b; };
union HalfU { bf16x4 b; u32x2 u; };

__device__ __forceinline__ f32x4 mfma16(bf16x8 a, bf16x8 b, f32x4 c) {
  return __builtin_amdgcn_mfma_f32_16x16x32_bf16(a, b, c, 0, 0, 0);
}

// elu = min(v, e^v - 1): identical for v<=0, exact for v>0, inf-safe.
__device__ __forceinline__ float elu1(float v) {
  return fminf(v, __expf(v) - 1.f);
}
__device__ __forceinline__ f32x4 elu4(f32x4 v) {
  f32x4 r;
  r.x = elu1(v.x); r.y = elu1(v.y); r.z = elu1(v.z); r.w = elu1(v.w);
  return r;
}

// pack two f32x4 (tile0 regs, tile1 regs) into a bf16x8 MFMA operand.
__device__ __forceinline__ bf16x8 pack2(f32x4 a, f32x4 b) {
  bf16x8 r;
  r[0] = (__bf16)a.x; r[1] = (__bf16)a.y; r[2] = (__bf16)a.z; r[3] = (__bf16)a.w;
  r[4] = (__bf16)b.x; r[5] = (__bf16)b.y; r[6] = (__bf16)b.z; r[7] = (__bf16)b.w;
  return r;
}

// hi/lo split pack of a full operand (weights/init use this).
__device__ __forceinline__ void packhl(f32x4 a, f32x4 b, bf16x8& hi, bf16x8& lo) {
  hi = pack2(a, b);
  f32x4 ra, rb;
  ra.x = (float)hi[0]; ra.y = (float)hi[1]; ra.z = (float)hi[2]; ra.w = (float)hi[3];
  rb.x = (float)hi[4]; rb.y = (float)hi[5]; rb.z = (float)hi[6]; rb.w = (float)hi[7];
  lo = pack2(a - ra, b - rb);
}

// half-operand hi/lo pack: one f32x4 tile -> 2 dwords hi + 2 dwords lo.
// Same element order as pack2's slots (little-endian bf16 pairs).
__device__ __forceinline__ void packh2(f32x4 v, u32x2& hi, u32x2& lo) {
  HalfU H, L;
  H.b[0] = (__bf16)v.x; H.b[1] = (__bf16)v.y;
  H.b[2] = (__bf16)v.z; H.b[3] = (__bf16)v.w;
  f32x4 r;
  r.x = (float)H.b[0]; r.y = (float)H.b[1];
  r.z = (float)H.b[2]; r.w = (float)H.b[3];
  f32x4 d = v - r;
  L.b[0] = (__bf16)d.x; L.b[1] = (__bf16)d.y;
  L.b[2] = (__bf16)d.z; L.b[3] = (__bf16)d.w;
  hi = H.u; lo = L.u;
}

__device__ __forceinline__ bf16x8 ldw(const float* rowp, int o1, int o2) {
  f32x4 a = *reinterpret_cast<const f32x4*>(rowp + o1);
  f32x4 b = *reinterpret_cast<const f32x4*>(rowp + o2);
  return pack2(a, b);
}
__device__ __forceinline__ void ldw2(const float* rowp, int o1, int o2,
                                     bf16x8& hi, bf16x8& lo) {
  f32x4 a = *reinterpret_cast<const f32x4*>(rowp + o1);
  f32x4 b = *reinterpret_cast<const f32x4*>(rowp + o2);
  packhl(a, b, hi, lo);
}

// tanh via exp + raw v_rcp (rel err ~1ulp fp32 -- far below bf16 noise).
__device__ __forceinline__ float tanh1(float x) {
  float t = __expf(2.f * x);
  return fmaf(-2.f, __builtin_amdgcn_rcpf(t + 1.f), 1.f);
}
__device__ __forceinline__ f32x4 tanh4(f32x4 v) {
  f32x4 r;
  r.x = tanh1(v.x); r.y = tanh1(v.y); r.z = tanh1(v.z); r.w = tanh1(v.w);
  return r;
}

// raw barrier: waits LDS ops only; vmcnt stays in flight across it.
#define STEP_BARRIER() asm volatile("s_waitcnt lgkmcnt(0)\ns_barrier" ::: "memory")

// ---------------------------------------------------------------------------
// prep_kernel: P0[b,t] = (bi0+bh0) + x[b,t] @ Wi0^T for all 131072 rows.
// (unchanged from R6, verified passing)
// ---------------------------------------------------------------------------
__global__ __launch_bounds__(256, 2) void prep_kernel(
    const float* __restrict__ x,
    const float* __restrict__ Wi0,
    const float* __restrict__ bi0, const float* __restrict__ bh0,
    float* __restrict__ p0)
{
  const int lane = threadIdx.x & 63;
  const int wv = threadIdx.x >> 6;
  const int q = lane >> 4, c = lane & 15;

  bf16x8 Wh[2][2], Wl[2][2];   // [kt][mt]
  #pragma unroll
  for (int kt = 0; kt < 2; ++kt)
    #pragma unroll
    for (int mt = 0; mt < 2; ++mt)
      ldw2(Wi0 + (16 * mt + c) * 64, 32 * kt + 4 * q, 32 * kt + 16 + 4 * q,
           Wh[kt][mt], Wl[kt][mt]);
  f32x4 B0[2];
  #pragma unroll
  for (int mt = 0; mt < 2; ++mt)
    B0[mt] = *reinterpret_cast<const f32x4*>(bi0 + 16 * mt + 4 * q) +
             *reinterpret_cast<const f32x4*>(bh0 + 16 * mt + 4 * q);

  const unsigned row = blockIdx.x * 64u + (unsigned)wv * 16u + (unsigned)c;
  const float* xp = x + (size_t)row * DIN;
  f32x4 x0 = *reinterpret_cast<const f32x4*>(xp + 4 * q);
  f32x4 x1 = *reinterpret_cast<const f32x4*>(xp + 16 + 4 * q);
  f32x4 x2 = *reinterpret_cast<const f32x4*>(xp + 32 + 4 * q);
  f32x4 x3 = *reinterpret_cast<const f32x4*>(xp + 48 + 4 * q);
  bf16x8 xf0 = pack2(x0, x1), xf1 = pack2(x2, x3);

  float* pout = p0 + (size_t)row * ZZ;
  #pragma unroll
  for (int mt = 0; mt < 2; ++mt) {
    f32x4 a = mfma16(Wh[0][mt], xf0, B0[mt]);
    a = mfma16(Wl[0][mt], xf0, a);
    a = mfma16(Wh[1][mt], xf1, a);
    a = mfma16(Wl[1][mt], xf1, a);
    *reinterpret_cast<f32x4*>(pout + 16 * mt + 4 * q) = a;
  }
}

// ---------------------------------------------------------------------------
// rnn_kernel: one chain per BLOCK of 4 waves -- per-step work split across
// 4 SIMDs. wave0/1: layer-0 d-tiles (3 MFMA); wave2/3: layer-1 e-tiles
// (6 MFMA). Packed bf16 hi/lo z exchanged via double-buffered LDS; one raw
// lgkmcnt+s_barrier per step (vmcnt prefetch stays in flight). Math is
// byte-identical to R6's verified recurrence.
// ---------------------------------------------------------------------------
__global__ __launch_bounds__(256, 1) void rnn_kernel(
    const float* __restrict__ p0buf,
    const float* __restrict__ Wh0,
    const float* __restrict__ Wi1, const float* __restrict__ Wh1,
    const float* __restrict__ bi1, const float* __restrict__ bh1,
    const float* __restrict__ h0g,
    float* __restrict__ rnn, float* __restrict__ out)
{
  // [buf][frag: zh0,zl0,zh1,zl1][lane*4 dwords]
  __shared__ __align__(16) unsigned int sh[2][4][256];

  const int lane = threadIdx.x & 63;
  const int wv = threadIdx.x >> 6;     // 0,1 = d-waves; 2,3 = e-waves
  const int q = lane >> 4, c = lane & 15;
  const int b0 = blockIdx.x * 16;
  const f32x4 Z4 = {0.f, 0.f, 0.f, 0.f};

  const float* pp = p0buf + (size_t)(b0 + c) * TT * ZZ;
  float* pr = rnn + (size_t)(b0 + c) * TT * ZZ;
  float* po = out + (size_t)(b0 + c) * TT * ZZ;

  const int mt = wv & 1;               // tile index within role
  const int dwoff = lane * 4 + mt * 2; // this wave's 2-dword slot

  if (wv < 2) {
    // =================== d-wave: layer 0, tile mt ===================
    bf16x8 W0h, W0l;
    ldw2(Wh0 + (16 * mt + c) * 32, 4 * q, 16 + 4 * q, W0h, W0l);
    const float* ppt = pp + 16 * mt + 4 * q;   // P tile base (per-lane)

    // init: write packed init-h0 tile into buf0
    {
      f32x4 u = *reinterpret_cast<const f32x4*>(h0g + 16 * mt + 4 * q);
      u32x2 hi, lo;
      packh2(u, hi, lo);
      *reinterpret_cast<u32x2*>(&sh[0][0][dwoff]) = hi;
      *reinterpret_cast<u32x2*>(&sh[0][1][dwoff]) = lo;
    }

    // P prefetch: 3 rotating regs, distance 3
    f32x4 Pa = *reinterpret_cast<const f32x4*>(ppt + (size_t)511 * ZZ);
    f32x4 Pb = *reinterpret_cast<const f32x4*>(ppt + (size_t)510 * ZZ);
    f32x4 Pc = *reinterpret_cast<const f32x4*>(ppt + (size_t)509 * ZZ);

    STEP_BARRIER();

    auto DSTEP = [&](int s, f32x4& Pm) {
      const int cur = s & 1;
      FragU z0, z1;
      z0.u = *reinterpret_cast<const u32x4*>(&sh[cur][0][lane * 4]);
      z1.u = *reinterpret_cast<const u32x4*>(&sh[cur][1][lane * 4]);
      f32x4 dm = mfma16(W0h, z0.b, Pm);
      f32x4 dl = mfma16(W0l, z0.b, mfma16(W0h, z1.b, Z4));
      {
        const int t = 511 - s;
        const int tl = t >= 3 ? t - 3 : 0;
        Pm = *reinterpret_cast<const f32x4*>(ppt + (size_t)tl * ZZ);
      }
      f32x4 d = tanh4(dm + dl);
      u32x2 hi, lo;
      packh2(d, hi, lo);
      *reinterpret_cast<u32x2*>(&sh[cur ^ 1][0][dwoff]) = hi;
      *reinterpret_cast<u32x2*>(&sh[cur ^ 1][1][dwoff]) = lo;
      STEP_BARRIER();
    };

    DSTEP(0, Pa);                         // s = 0 (t = 511)
    #pragma unroll 1
    for (int g = 0; g < 170; ++g) {       // s = 1..510
      DSTEP(1 + 3 * g, Pb);
      DSTEP(2 + 3 * g, Pc);
      DSTEP(3 + 3 * g, Pa);
    }
    DSTEP(511, Pb);                       // s = 511 (t = 0)
  } else {
    // =================== e-wave: layer 1, tile mt ===================
    bf16x8 W1h0, W1l0, W1h1, W1l1;
    ldw2(Wi1 + (16 * mt + c) * 32, 4 * q, 16 + 4 * q, W1h0, W1l0);
    ldw2(Wh1 + (16 * mt + c) * 32, 4 * q, 16 + 4 * q, W1h1, W1l1);
    f32x4 B1 = *reinterpret_cast<const f32x4*>(bi1 + 16 * mt + 4 * q) +
               *reinterpret_cast<const f32x4*>(bh1 + 16 * mt + 4 * q);

    STEP_BARRIER();

    // s = 0: no compute; write packed init-h1 tile into buf1
    {
      f32x4 u = *reinterpret_cast<const f32x4*>(h0g + 32 + 16 * mt + 4 * q);
      u32x2 hi, lo;
      packh2(u, hi, lo);
      *reinterpret_cast<u32x2*>(&sh[1][2][dwoff]) = hi;
      *reinterpret_cast<u32x2*>(&sh[1][3][dwoff]) = lo;
      STEP_BARRIER();
    }

    auto ESTEP = [&](int s) {
      const int cur = s & 1;
      FragU zh0, zl0, zh1, zl1;
      zh0.u = *reinterpret_cast<const u32x4*>(&sh[cur][0][lane * 4]);
      zl0.u = *reinterpret_cast<const u32x4*>(&sh[cur][1][lane * 4]);
      zh1.u = *reinterpret_cast<const u32x4*>(&sh[cur][2][lane * 4]);
      zl1.u = *reinterpret_cast<const u32x4*>(&sh[cur][3][lane * 4]);
      f32x4 ea = mfma16(W1h1, zh1.b, mfma16(W1h0, zh0.b, B1));
      f32x4 eb = mfma16(W1h1, zl1.b, mfma16(W1h0, zl0.b, Z4));
      f32x4 ec = mfma16(W1l1, zh1.b, mfma16(W1l0, zh0.b, Z4));
      f32x4 e = tanh4(ea + (eb + ec));
      const int t = 511 - s;
      float* prt = pr + (size_t)(t + 1) * ZZ + 16 * mt + 4 * q;
      *reinterpret_cast<f32x4*>(prt) = e;
      if (t == 510) {
        float* pot = po + (size_t)511 * ZZ + 16 * mt + 4 * q;
        *reinterpret_cast<f32x4*>(pot) = e;
      }
      u32x2 hi, lo;
      packh2(e, hi, lo);
      *reinterpret_cast<u32x2*>(&sh[cur ^ 1][2][dwoff]) = hi;
      *reinterpret_cast<u32x2*>(&sh[cur ^ 1][3][dwoff]) = lo;
      STEP_BARRIER();
    };

    #pragma unroll 1
    for (int g = 0; g < 170; ++g) {       // s = 1..510
      ESTEP(1 + 3 * g);
      ESTEP(2 + 3 * g);
      ESTEP(3 + 3 * g);
    }
    ESTEP(511);                           // s = 511 -> stores rnn row 1
  }
}

// ---------------------------------------------------------------------------
// ODE kernel: unchanged from R6 (verified passing).
// ---------------------------------------------------------------------------
__global__ __launch_bounds__(256, 2) void ode_kernel(
    const float* __restrict__ rnn,
    const float* __restrict__ w1, const float* __restrict__ b1,
    const float* __restrict__ w2, const float* __restrict__ b2,
    const float* __restrict__ w3, const float* __restrict__ b3,
    float* __restrict__ out)
{
  const int lane = threadIdx.x & 63;
  const int wv = threadIdx.x >> 6;
  const int q = lane >> 4, c = lane & 15;

  bf16x8 W1[4], W2[2][4], W3[2][2];
  f32x4 BZ1[4], BZ2[4], BZ3[2];
  #pragma unroll
  for (int mt = 0; mt < 4; ++mt) {
    W1[mt] = ldw(w1 + (16 * mt + c) * 32, 4 * q, 16 + 4 * q);
    BZ1[mt] = *reinterpret_cast<const f32x4*>(b1 + 16 * mt + 4 * q);
    BZ2[mt] = *reinterpret_cast<const f32x4*>(b2 + 16 * mt + 4 * q);
  }
  #pragma unroll
  for (int kt = 0; kt < 2; ++kt)
    #pragma unroll
    for (int mt = 0; mt < 4; ++mt)
      W2[kt][mt] = ldw(w2 + (16 * mt + c) * 64, 32 * kt + 4 * q, 32 * kt + 16 + 4 * q);
  #pragma unroll
  for (int kt = 0; kt < 2; ++kt)
    #pragma unroll
    for (int mt = 0; mt < 2; ++mt)
      W3[kt][mt] = ldw(w3 + (16 * mt + c) * 64, 32 * kt + 4 * q, 32 * kt + 16 + 4 * q);
  #pragma unroll
  for (int mt = 0; mt < 2; ++mt)
    BZ3[mt] = *reinterpret_cast<const f32x4*>(b3 + 16 * mt + 4 * q);

  const unsigned row = 16u * (blockIdx.x * 4u + (unsigned)wv) + (unsigned)c;
  const unsigned bb = row / 511u, tp = row - bb * 511u;
  const float* srcp = rnn + ((size_t)bb * TT + tp + 1) * ZZ;
  f32x4 y0 = *reinterpret_cast<const f32x4*>(srcp + 4 * q);
  f32x4 y1 = *reinterpret_cast<const f32x4*>(srcp + 16 + 4 * q);

  f32x4 k0, k1, ks0, ks1;

  auto feval = [&](bf16x8 xf, f32x4& o0, f32x4& o1) {
    f32x4 a[4];
    #pragma unroll
    for (int mt = 0; mt < 4; ++mt) a[mt] = mfma16(W1[mt], xf, BZ1[mt]);
    #pragma unroll
    for (int mt = 0; mt < 4; ++mt) a[mt] = elu4(a[mt]);
    bf16x8 h10 = pack2(a[0], a[1]), h11 = pack2(a[2], a[3]);
    f32x4 g[4];
    #pragma unroll
    for (int mt = 0; mt < 4; ++mt)
      g[mt] = mfma16(W2[1][mt], h11, mfma16(W2[0][mt], h10, BZ2[mt]));
    #pragma unroll
    for (int mt = 0; mt < 4; ++mt) g[mt] = elu4(g[mt]);
    bf16x8 h20 = pack2(g[0], g[1]), h21 = pack2(g[2], g[3]);
    o0 = mfma16(W3[1][0], h21, mfma16(W3[0][0], h20, BZ3[0]));
    o1 = mfma16(W3[1][1], h21, mfma16(W3[0][1], h20, BZ3[1]));
  };

  const float hs = 0.01f;
  #pragma unroll 1
  for (int it = 0; it < 9; ++it) {
    feval(pack2(y0, y1), k0, k1);
    ks0 = k0; ks1 = k1;
    feval(pack2(y0 + (0.5f * hs) * k0, y1 + (0.5f * hs) * k1), k0, k1);
    ks0 += 2.f * k0; ks1 += 2.f * k1;
    feval(pack2(y0 + (0.5f * hs) * k0, y1 + (0.5f * hs) * k1), k0, k1);
    ks0 += 2.f * k0; ks1 += 2.f * k1;
    feval(pack2(y0 + hs * k0, y1 + hs * k1), k0, k1);
    y0 += (hs / 6.f) * (ks0 + k0);
    y1 += (hs / 6.f) * (ks1 + k1);
  }

  float* dstp = out + ((size_t)bb * TT + tp) * ZZ;
  *reinterpret_cast<f32x4*>(dstp + 4 * q) = y0;
  *reinterpret_cast<f32x4*>(dstp + 16 + 4 * q) = y1;
}

// ---------------------------------------------------------------------------
extern "C" void kernel_launch(void* const* d_in, const int* in_sizes, int n_in,
                              void* d_out, int out_size, void* d_ws, size_t ws_size,
                              hipStream_t stream) {
  const float* x   = (const float*)d_in[0];
  const float* Wi0 = (const float*)d_in[1];
  const float* Wh0 = (const float*)d_in[2];
  const float* bi0 = (const float*)d_in[3];
  const float* bh0 = (const float*)d_in[4];
  const float* Wi1 = (const float*)d_in[5];
  const float* Wh1 = (const float*)d_in[6];
  const float* bi1 = (const float*)d_in[7];
  const float* bh1 = (const float*)d_in[8];
  const float* h0  = (const float*)d_in[9];
  const float* w1  = (const float*)d_in[10];
  const float* b1  = (const float*)d_in[11];
  const float* w2  = (const float*)d_in[12];
  const float* b2  = (const float*)d_in[13];
  const float* w3  = (const float*)d_in[14];
  const float* b3  = (const float*)d_in[15];
  float* out = (float*)d_out;
  float* rnn = (float*)d_ws;      // B*T*Z fp32 = 16.7 MB scratch
  float* p0  = (float*)d_out;     // d_out doubles as P0 scratch; every byte
                                  // is overwritten later (ode rows 0..510,
                                  // rnn row 511) before validation.

  prep_kernel<<<2048, 256, 0, stream>>>(x, Wi0, bi0, bh0, p0);
  // 16 chains, one per block of 4 waves (4 SIMDs each)
  rnn_kernel<<<16, 256, 0, stream>>>(p0, Wh0, Wi1, Wh1, bi1, bh1, h0, rnn, out);
  ode_kernel<<<2044, 256, 0, stream>>>(rnn, w1, b1, w2, b2, w3, b3, out);
}